// Round 1
// baseline (208.083 us; speedup 1.0000x reference)
//
#include <hip/hip_runtime.h>
#include <stdint.h>

// B=8, OBJ=128, INP=64, HID=256, D=192.
// R22: occupancy restructure. Theory: pair_kernel is latency-bound at 25%
// occupancy (64KB LDS -> 2 blocks/CU); MFMA busy time (13.8us) is already at
// the 2.5PF floor, 53% of wall is stall. Change: split j into two 64-row
// passes per block -> hbuf 32KB, acc[2][2] (64 regs), af ring-2, pooled sums
// accumulated in 1KB LDS (ms). Targets __launch_bounds__(256,4): 4 blocks/CU,
// grid 1024 = 256CU x 4 -> ALL blocks co-resident, one round, barriers and
// epilogue overlap across 4 resident blocks. wt is re-read per pass (L2 is
// idle; latency is the bottleneck, not bandwidth). Setup kernel unchanged.

#define HID 256
#define NOBJ 128
#define NROW 1024   // B*OBJ

typedef __attribute__((ext_vector_type(8))) short short8;
typedef __attribute__((ext_vector_type(4))) float float4v;
typedef __attribute__((ext_vector_type(16))) float float16v;
typedef __attribute__((ext_vector_type(2))) unsigned int uint2v;

__device__ __forceinline__ unsigned int f2bf_u(float f) {
    unsigned int u = __builtin_bit_cast(unsigned int, f);
    u += 0x7fffu + ((u >> 16) & 1u);   // RNE
    return u >> 16;
}
__device__ __forceinline__ unsigned int pack2(float a, float b) {
    return f2bf_u(a) | (f2bf_u(b) << 16);
}
__device__ __forceinline__ float relu(float v) { return v > 0.f ? v : 0.f; }

// LDS-only barrier: leaves global-load (vmcnt) prefetches in flight.
__device__ __forceinline__ void lds_barrier() {
    asm volatile("s_waitcnt lgkmcnt(0)\n\ts_barrier" ::: "memory");
}

// ---- setup:
//  blocks [0,16): fragment-major pack of w1,w2 (layer m = bx>>3, n-tile tau = bx&7)
//  blocks [16,528): encoder, 2 rows each (fold b_enc into ea)
//  blocks [528,784): W34 row m = bx-528:  W34[m][o] = sum_k w3[m][k]*wd1[k][o]
//  block  784:       b34[o] = sum_k b3[k]*wd1[k][o] + bd1[o]
__global__ void setup_kernel(const float* __restrict__ x0, const float* __restrict__ x1,
                             const float* __restrict__ x2, const float* __restrict__ w_enc,
                             const float* __restrict__ b_enc,
                             const float* __restrict__ w1, const float* __restrict__ w2,
                             const float* __restrict__ w3, const float* __restrict__ b3,
                             const float* __restrict__ wd1, const float* __restrict__ bd1,
                             unsigned short* __restrict__ wt,
                             float* __restrict__ ea, float* __restrict__ eb,
                             float* __restrict__ W34, float* __restrict__ b34) {
    const int bx = blockIdx.x, t = threadIdx.x;
    __shared__ float lw[256][33];          // [k][n-within-tile]
    __shared__ float xs[2][192];
    if (bx < 16) {
        const int m = bx >> 3, tau = bx & 7;
        const float* w = (m == 0) ? w1 : w2;
        const int n = t & 31, kk = t >> 5;     // 8 k-rows per pass
#pragma unroll
        for (int rep = 0; rep < 32; ++rep) {
            int k = rep * 8 + kk;
            lw[k][n] = w[k * 256 + tau * 32 + n];   // coalesced 128B segments
        }
        __syncthreads();
        unsigned short* outp = wt + (m * 8 + tau) * 8192;
        const int lane = t & 63, wq = t >> 6;
        const int h5 = lane >> 5, l31n = lane & 31;
#pragma unroll
        for (int rep = 0; rep < 4; ++rep) {
            const int kb = wq * 4 + rep;
            short8 v;
#pragma unroll
            for (int e = 0; e < 8; ++e)
                v[e] = (short)f2bf_u(lw[kb * 16 + h5 * 8 + e][l31n]);
            *(short8*)(outp + kb * 512 + lane * 8) = v;   // wave-contiguous 1KB
        }
        return;
    }
    if (bx < 528) {
        const int e = bx - 16;                 // 512 groups x 2 rows
        for (int idx = t; idx < 384; idx += 256) {
            int r = idx / 192, d = idx % 192;
            int row = e * 2 + r;
            float v = (d < 64) ? x0[row * 64 + d]
                    : (d < 128) ? x1[row * 64 + d - 64]
                    : x2[row * 64 + d - 128];
            xs[r][d] = v;
        }
        __syncthreads();
        float aA[2] = {0.f, 0.f}, aB[2] = {0.f, 0.f};
#pragma unroll 16
        for (int d = 0; d < 192; ++d) {
            float wa = w_enc[d * 256 + t];
            float wb = w_enc[(192 + d) * 256 + t];
#pragma unroll
            for (int r = 0; r < 2; ++r) { aA[r] += xs[r][d] * wa; aB[r] += xs[r][d] * wb; }
        }
        float be = b_enc[t];
#pragma unroll
        for (int r = 0; r < 2; ++r) {
            ea[(e * 2 + r) * 256 + t] = aA[r] + be;
            eb[(e * 2 + r) * 256 + t] = aB[r];
        }
        return;
    }
    if (bx < 784) {
        const int m = bx - 528;
        float a = 0.f;
#pragma unroll 8
        for (int k = 0; k < 256; ++k) a += w3[m * 256 + k] * wd1[k * 256 + t];
        W34[m * 256 + t] = a;
        return;
    }
    {   // b34
        float a = bd1[t];
#pragma unroll 8
        for (int k = 0; k < 256; ++k) a += b3[k] * wd1[k * 256 + t];
        b34[t] = a;
    }
}

// ---- pair MLP (2 layers) + fused decoder: grid 1024, one WG per (b,i).
//      j processed in TWO 64-row passes; 32KB LDS h + 1KB pooled accumulator.
//      swizzle: elem(j,k) at j*256 + ((k>>3 ^ (j&31))<<3) + (k&7).
//      Wave wv owns n-quarter n0=wv*64 as tn=2 x tj=2 tiles of 32x32x16.
//      af ring-2 (prefetch distance 1); TLP (4 blocks/CU) hides the rest.
__global__ __launch_bounds__(256, 4) void pair_kernel(
        const float* __restrict__ ea, const float* __restrict__ eb,
        const unsigned short* __restrict__ wt,
        const float* __restrict__ b1, const float* __restrict__ b2,
        const float* __restrict__ W34, const float* __restrict__ b34,
        const float* __restrict__ wd2, const float* __restrict__ bd2,
        float* __restrict__ out) {
    __shared__ __align__(16) unsigned short hbuf[64 * 256];   // 32 KB
    __shared__ float ms[HID];   // pooled (mean over j) accumulator, per-n

    const int w = blockIdx.x, b = w >> 7;
    const int t = threadIdx.x, wv = t >> 6, lane = t & 63;
    const int l31 = lane & 31, h5 = lane >> 5;
    const int n0 = wv * 64;

    const unsigned short* aptr = wt + lane * 8;   // + ((l*8 + wv*2+tn)*16 + kb)*512

    short8 af[2][2], bfr[2][2];
    float16v acc[2][2];   // [tn][tj]

#pragma unroll 1
    for (int pass = 0; pass < 2; ++pass) {
        // issue g=0 weight-fragment loads early; latency hides under preamble
#pragma unroll
        for (int tn = 0; tn < 2; ++tn)
            af[0][tn] = *(const short8*)(aptr + ((wv * 2 + tn) * 16) * 512);

        // preamble: h0[j][k] = relu(ea[w][k] + eb[b*128 + pass*64 + j][k])
        // wave fills rows j = wv*16 .. wv*16+15 (j is LOCAL to this pass)
        {
            const float4v va = *(const float4v*)(ea + w * 256 + lane * 4);
            const float* ebbase = eb + (b * NOBJ + pass * 64) * 256;
            const int c = lane >> 1, sub = (lane & 1) * 4;
#pragma unroll 4
            for (int jj = 0; jj < 16; ++jj) {
                const int j = wv * 16 + jj;
                float4v vb = *(const float4v*)(ebbase + j * 256 + lane * 4);
                int addr = j * 256 + ((c ^ (j & 31)) << 3) + sub;
                *(uint2v*)(hbuf + addr) = (uint2v){
                    pack2(relu(va[0] + vb[0]), relu(va[1] + vb[1])),
                    pack2(relu(va[2] + vb[2]), relu(va[3] + vb[3]))};
            }
        }
        lds_barrier();

        int jb[2];
#pragma unroll
        for (int tj = 0; tj < 2; ++tj) jb[tj] = (tj * 32 + l31) * 256;
#pragma unroll
        for (int tj = 0; tj < 2; ++tj)
            bfr[0][tj] = *(const short8*)(hbuf + jb[tj] + ((h5 ^ l31) << 3));

#pragma unroll
        for (int l = 0; l < 2; ++l) {
            const float* bias = (l == 0) ? b1 : b2;
#pragma unroll
            for (int tn = 0; tn < 2; ++tn)
#pragma unroll
                for (int q = 0; q < 4; ++q) {
                    float4v bv = *(const float4v*)(bias + n0 + tn * 32 + q * 8 + h5 * 4);
#pragma unroll
                    for (int i = 0; i < 4; ++i)
#pragma unroll
                        for (int tj = 0; tj < 2; ++tj)
                            acc[tn][tj][q * 4 + i] = bv[i];
                }
#pragma unroll
            for (int kb = 0; kb < 16; ++kb) {
                const int g = l * 16 + kb, gp = g + 1;
                if (gp < 32) {   // ring-2: prefetch next step's weight frags
                    const int lp = gp >> 4, kp = gp & 15;
#pragma unroll
                    for (int tn = 0; tn < 2; ++tn)
                        af[gp & 1][tn] = *(const short8*)(aptr + ((lp * 8 + wv * 2 + tn) * 16 + kp) * 512);
                }
                if (kb < 15) {   // prefetch next step's B from LDS
                    const int off = ((((kb + 1) * 2 + h5) ^ l31) << 3);
#pragma unroll
                    for (int tj = 0; tj < 2; ++tj)
                        bfr[(kb + 1) & 1][tj] = *(const short8*)(hbuf + jb[tj] + off);
                }
#pragma unroll
                for (int tn = 0; tn < 2; ++tn)
#pragma unroll
                    for (int tj = 0; tj < 2; ++tj)
                        acc[tn][tj] = __builtin_amdgcn_mfma_f32_32x32x16_bf16(
                            af[g & 1][tn], bfr[kb & 1][tj], acc[tn][tj], 0, 0, 0);
            }
            lds_barrier();   // hbuf reads of layer l done

            if (l == 0) {
                // writeback h1 (relu, bf16) into swizzled layout
#pragma unroll
                for (int tn = 0; tn < 2; ++tn)
#pragma unroll
                    for (int q = 0; q < 4; ++q) {
                        const int nb_ = n0 + tn * 32 + 8 * q + 4 * h5;
                        const int cn = nb_ >> 3, sub = nb_ & 7;
#pragma unroll
                        for (int tj = 0; tj < 2; ++tj) {
                            const int j = tj * 32 + l31;
                            int addr = j * 256 + ((cn ^ l31) << 3) + sub;
                            *(uint2v*)(hbuf + addr) = (uint2v){
                                pack2(relu(acc[tn][tj][q * 4]), relu(acc[tn][tj][q * 4 + 1])),
                                pack2(relu(acc[tn][tj][q * 4 + 2]), relu(acc[tn][tj][q * 4 + 3]))};
                        }
                    }
                lds_barrier();
#pragma unroll
                for (int tj = 0; tj < 2; ++tj)
                    bfr[0][tj] = *(const short8*)(hbuf + jb[tj] + ((h5 ^ l31) << 3));
            }
        }

        // partial pooled sum over this pass's 64 j rows:
        // col j = l31, row n = n0 + tn*32 + (r&3) + 8*(r>>2) + 4*h5
#pragma unroll
        for (int tn = 0; tn < 2; ++tn)
#pragma unroll
            for (int r = 0; r < 16; ++r) {
                float s = relu(acc[tn][0][r]) + relu(acc[tn][1][r]);
                s += __shfl_xor(s, 1);
                s += __shfl_xor(s, 2);
                s += __shfl_xor(s, 4);
                s += __shfl_xor(s, 8);
                s += __shfl_xor(s, 16);
                if (l31 == 0) {
                    const int n = n0 + tn * 32 + (r & 3) + 8 * (r >> 2) + 4 * h5;
                    if (pass == 0) ms[n] = s;
                    else           ms[n] = (ms[n] + s) * 0.0078125f;   // /128
                }
            }
    }
    __syncthreads();

    // ---- epilogue: t1 = relu(m2@W34 + b34); out = t1@wd2 + bd2
    // fs aliases hbuf (all h reads done): p1[0..1024) | t1[1024..1280) | p2[1280..1536)
    float* fs = (float*)hbuf;
    {   // stage 1: m2 @ W34, 4-way k-split (wave wv covers k in [wv*64, wv*64+64))
        float p0 = 0.f, p1 = 0.f, p2 = 0.f, p3 = 0.f;
        const float* wp = W34 + (wv * 64) * 256 + lane;
#pragma unroll 8
        for (int kk = 0; kk < 64; ++kk) {
            float mv = ms[wv * 64 + kk];
            p0 += mv * wp[kk * 256];
            p1 += mv * wp[kk * 256 + 64];
            p2 += mv * wp[kk * 256 + 128];
            p3 += mv * wp[kk * 256 + 192];
        }
        fs[wv * 256 + lane]       = p0;
        fs[wv * 256 + 64 + lane]  = p1;
        fs[wv * 256 + 128 + lane] = p2;
        fs[wv * 256 + 192 + lane] = p3;
    }
    __syncthreads();
    fs[1024 + t] = relu(fs[t] + fs[256 + t] + fs[512 + t] + fs[768 + t] + b34[t]);
    __syncthreads();
    {   // stage 2: t1 @ wd2 (wave wv covers k in [wv*64, wv*64+64), lane = output o)
        float p = 0.f;
        const float* w2p = wd2 + (wv * 64) * 64 + lane;
#pragma unroll 8
        for (int kk = 0; kk < 64; ++kk) p += fs[1024 + wv * 64 + kk] * w2p[kk * 64];
        fs[1280 + wv * 64 + lane] = p;
    }
    __syncthreads();
    if (t < 64)
        out[w * 64 + t] = fs[1280 + t] + fs[1344 + t] + fs[1408 + t] + fs[1472 + t] + bd2[t];
}

extern "C" void kernel_launch(void* const* d_in, const int* in_sizes, int n_in,
                              void* d_out, int out_size, void* d_ws, size_t ws_size,
                              hipStream_t stream) {
    const float* x0    = (const float*)d_in[0];
    const float* x1    = (const float*)d_in[1];
    const float* x2    = (const float*)d_in[2];
    const float* w_enc = (const float*)d_in[3];
    const float* b_enc = (const float*)d_in[4];
    const float* w1    = (const float*)d_in[5];
    const float* b1    = (const float*)d_in[6];
    const float* w2    = (const float*)d_in[7];
    const float* b2    = (const float*)d_in[8];
    const float* w3    = (const float*)d_in[9];
    const float* b3    = (const float*)d_in[10];
    const float* wd1   = (const float*)d_in[11];
    const float* bd1   = (const float*)d_in[12];
    const float* wd2   = (const float*)d_in[13];
    const float* bd2   = (const float*)d_in[14];
    float* out = (float*)d_out;

    // workspace: wfrag 256KB (in 384KB slot) | ea 1MB | eb 1MB | W34 256KB | b34 1KB
    unsigned short* wt = (unsigned short*)d_ws;
    float* ea  = (float*)((char*)d_ws + 3 * 65536 * sizeof(unsigned short));
    float* eb  = ea + NROW * HID;
    float* W34 = eb + NROW * HID;
    float* b34 = W34 + 256 * 256;

    setup_kernel<<<785, 256, 0, stream>>>(x0, x1, x2, w_enc, b_enc, w1, w2,
                                          w3, b3, wd1, bd1, wt, ea, eb, W34, b34);
    pair_kernel<<<NROW, 256, 0, stream>>>(ea, eb, wt, b1, b2, W34, b34, wd2, bd2, out);
}

// Round 2
// 194.146 us; speedup vs baseline: 1.0718x; 1.0718x over previous
//
#include <hip/hip_runtime.h>
#include <stdint.h>

// B=8, OBJ=128, INP=64, HID=256, D=192.
// R23: occupancy restructure, take 2. R22 (256thr, launch_bounds(256,4))
// spilled: acc64+af+bfr+addr ~160 regs vs 128 cap -> 270MB scratch traffic
// (FETCH 137MB / WRITE 133MB), 117us. Fix: 512-thread blocks, 8 waves, each
// wave owns a 32-wide n-slice (tn=1): acc 32, bfr 16, af ring-4 16 -> ~110
// unified regs, fits the 128 cap of launch_bounds(512,4) WITHOUT spilling.
// Two-pass j-split keeps hbuf at 32KB (+1KB ms) -> 2 blocks/CU resident =
// 4 waves/SIMD = 50% occupancy, grid 1024 = exactly 2 rounds of 512.
// MFMA floor unchanged (13.8us); 4 waves/SIMD hide barrier drains + L2 lat.
// Setup kernel byte-identical to R20/R22.

#define HID 256
#define NOBJ 128
#define NROW 1024   // B*OBJ

typedef __attribute__((ext_vector_type(8))) short short8;
typedef __attribute__((ext_vector_type(4))) float float4v;
typedef __attribute__((ext_vector_type(16))) float float16v;
typedef __attribute__((ext_vector_type(2))) unsigned int uint2v;

__device__ __forceinline__ unsigned int f2bf_u(float f) {
    unsigned int u = __builtin_bit_cast(unsigned int, f);
    u += 0x7fffu + ((u >> 16) & 1u);   // RNE
    return u >> 16;
}
__device__ __forceinline__ unsigned int pack2(float a, float b) {
    return f2bf_u(a) | (f2bf_u(b) << 16);
}
__device__ __forceinline__ float relu(float v) { return v > 0.f ? v : 0.f; }

// LDS-only barrier: leaves global-load (vmcnt) prefetches in flight.
__device__ __forceinline__ void lds_barrier() {
    asm volatile("s_waitcnt lgkmcnt(0)\n\ts_barrier" ::: "memory");
}

// ---- setup:
//  blocks [0,16): fragment-major pack of w1,w2 (layer m = bx>>3, n-tile tau = bx&7)
//  blocks [16,528): encoder, 2 rows each (fold b_enc into ea)
//  blocks [528,784): W34 row m = bx-528:  W34[m][o] = sum_k w3[m][k]*wd1[k][o]
//  block  784:       b34[o] = sum_k b3[k]*wd1[k][o] + bd1[o]
__global__ void setup_kernel(const float* __restrict__ x0, const float* __restrict__ x1,
                             const float* __restrict__ x2, const float* __restrict__ w_enc,
                             const float* __restrict__ b_enc,
                             const float* __restrict__ w1, const float* __restrict__ w2,
                             const float* __restrict__ w3, const float* __restrict__ b3,
                             const float* __restrict__ wd1, const float* __restrict__ bd1,
                             unsigned short* __restrict__ wt,
                             float* __restrict__ ea, float* __restrict__ eb,
                             float* __restrict__ W34, float* __restrict__ b34) {
    const int bx = blockIdx.x, t = threadIdx.x;
    __shared__ float lw[256][33];          // [k][n-within-tile]
    __shared__ float xs[2][192];
    if (bx < 16) {
        const int m = bx >> 3, tau = bx & 7;
        const float* w = (m == 0) ? w1 : w2;
        const int n = t & 31, kk = t >> 5;     // 8 k-rows per pass
#pragma unroll
        for (int rep = 0; rep < 32; ++rep) {
            int k = rep * 8 + kk;
            lw[k][n] = w[k * 256 + tau * 32 + n];   // coalesced 128B segments
        }
        __syncthreads();
        unsigned short* outp = wt + (m * 8 + tau) * 8192;
        const int lane = t & 63, wq = t >> 6;
        const int h5 = lane >> 5, l31n = lane & 31;
#pragma unroll
        for (int rep = 0; rep < 4; ++rep) {
            const int kb = wq * 4 + rep;
            short8 v;
#pragma unroll
            for (int e = 0; e < 8; ++e)
                v[e] = (short)f2bf_u(lw[kb * 16 + h5 * 8 + e][l31n]);
            *(short8*)(outp + kb * 512 + lane * 8) = v;   // wave-contiguous 1KB
        }
        return;
    }
    if (bx < 528) {
        const int e = bx - 16;                 // 512 groups x 2 rows
        for (int idx = t; idx < 384; idx += 256) {
            int r = idx / 192, d = idx % 192;
            int row = e * 2 + r;
            float v = (d < 64) ? x0[row * 64 + d]
                    : (d < 128) ? x1[row * 64 + d - 64]
                    : x2[row * 64 + d - 128];
            xs[r][d] = v;
        }
        __syncthreads();
        float aA[2] = {0.f, 0.f}, aB[2] = {0.f, 0.f};
#pragma unroll 16
        for (int d = 0; d < 192; ++d) {
            float wa = w_enc[d * 256 + t];
            float wb = w_enc[(192 + d) * 256 + t];
#pragma unroll
            for (int r = 0; r < 2; ++r) { aA[r] += xs[r][d] * wa; aB[r] += xs[r][d] * wb; }
        }
        float be = b_enc[t];
#pragma unroll
        for (int r = 0; r < 2; ++r) {
            ea[(e * 2 + r) * 256 + t] = aA[r] + be;
            eb[(e * 2 + r) * 256 + t] = aB[r];
        }
        return;
    }
    if (bx < 784) {
        const int m = bx - 528;
        float a = 0.f;
#pragma unroll 8
        for (int k = 0; k < 256; ++k) a += w3[m * 256 + k] * wd1[k * 256 + t];
        W34[m * 256 + t] = a;
        return;
    }
    {   // b34
        float a = bd1[t];
#pragma unroll 8
        for (int k = 0; k < 256; ++k) a += b3[k] * wd1[k * 256 + t];
        b34[t] = a;
    }
}

// ---- pair MLP (2 layers) + fused decoder: grid 1024, one WG (512 thr) per (b,i).
//      j processed in TWO 64-row passes; 32KB LDS h + 1KB pooled accumulator.
//      swizzle: elem(j,k) at j*256 + ((k>>3 ^ (j&31))<<3) + (k&7).
//      8 waves: wave wv owns n-slice n0=wv*32 as tj=2 tiles of 32x32x16.
//      acc 32 regs, af ring-4 (distance 3), bfr double-buffered.
__global__ __launch_bounds__(512, 4) void pair_kernel(
        const float* __restrict__ ea, const float* __restrict__ eb,
        const unsigned short* __restrict__ wt,
        const float* __restrict__ b1, const float* __restrict__ b2,
        const float* __restrict__ W34, const float* __restrict__ b34,
        const float* __restrict__ wd2, const float* __restrict__ bd2,
        float* __restrict__ out) {
    __shared__ __align__(16) unsigned short hbuf[64 * 256];   // 32 KB
    __shared__ float ms[HID];   // pooled (sum over j) accumulator, per-n

    const int w = blockIdx.x, b = w >> 7;
    const int t = threadIdx.x, wv = t >> 6, lane = t & 63;
    const int l31 = lane & 31, h5 = lane >> 5;
    const int n0 = wv * 32;

    const unsigned short* aptr = wt + lane * 8;   // + ((l*8 + wv)*16 + kb)*512

    short8 af[4], bfr[2][2];
    float16v acc[2];   // [tj]

#pragma unroll 1
    for (int pass = 0; pass < 2; ++pass) {
        // ring-4 preload: steps g = 0,1,2 of layer 0 (latency hides under preamble)
#pragma unroll
        for (int pg = 0; pg < 3; ++pg)
            af[pg] = *(const short8*)(aptr + (wv * 16 + pg) * 512);

        // preamble: h0[j][k] = relu(ea[w][k] + eb[b*128 + pass*64 + j][k])
        // wave fills rows j = wv*8 .. wv*8+7 (j is LOCAL to this pass)
        {
            const float4v va = *(const float4v*)(ea + w * 256 + lane * 4);
            const float* ebbase = eb + (b * NOBJ + pass * 64) * 256;
            const int c = lane >> 1, sub = (lane & 1) * 4;
#pragma unroll 4
            for (int jj = 0; jj < 8; ++jj) {
                const int j = wv * 8 + jj;
                float4v vb = *(const float4v*)(ebbase + j * 256 + lane * 4);
                int addr = j * 256 + ((c ^ (j & 31)) << 3) + sub;
                *(uint2v*)(hbuf + addr) = (uint2v){
                    pack2(relu(va[0] + vb[0]), relu(va[1] + vb[1])),
                    pack2(relu(va[2] + vb[2]), relu(va[3] + vb[3]))};
            }
        }
        lds_barrier();

        int jb[2];
#pragma unroll
        for (int tj = 0; tj < 2; ++tj) jb[tj] = (tj * 32 + l31) * 256;
#pragma unroll
        for (int tj = 0; tj < 2; ++tj)
            bfr[0][tj] = *(const short8*)(hbuf + jb[tj] + ((h5 ^ l31) << 3));

#pragma unroll
        for (int l = 0; l < 2; ++l) {
            const float* bias = (l == 0) ? b1 : b2;
#pragma unroll
            for (int q = 0; q < 4; ++q) {
                float4v bv = *(const float4v*)(bias + n0 + q * 8 + h5 * 4);
#pragma unroll
                for (int i = 0; i < 4; ++i)
#pragma unroll
                    for (int tj = 0; tj < 2; ++tj)
                        acc[tj][q * 4 + i] = bv[i];
            }
#pragma unroll
            for (int kb = 0; kb < 16; ++kb) {
                const int g = l * 16 + kb, gp = g + 3;
                if (gp < 32) {   // ring-4: prefetch 3 steps ahead (crosses layers)
                    const int lp = gp >> 4, kp = gp & 15;
                    af[gp & 3] = *(const short8*)(aptr + ((lp * 8 + wv) * 16 + kp) * 512);
                }
                if (kb < 15) {   // prefetch next step's B from LDS
                    const int off = ((((kb + 1) * 2 + h5) ^ l31) << 3);
#pragma unroll
                    for (int tj = 0; tj < 2; ++tj)
                        bfr[(kb + 1) & 1][tj] = *(const short8*)(hbuf + jb[tj] + off);
                }
#pragma unroll
                for (int tj = 0; tj < 2; ++tj)
                    acc[tj] = __builtin_amdgcn_mfma_f32_32x32x16_bf16(
                        af[g & 3], bfr[kb & 1][tj], acc[tj], 0, 0, 0);
            }
            lds_barrier();   // hbuf reads of layer l done

            if (l == 0) {
                // writeback h1 (relu, bf16) into swizzled layout
#pragma unroll
                for (int q = 0; q < 4; ++q) {
                    const int nb_ = n0 + 8 * q + 4 * h5;
                    const int cn = nb_ >> 3, sub = nb_ & 7;
#pragma unroll
                    for (int tj = 0; tj < 2; ++tj) {
                        const int j = tj * 32 + l31;
                        int addr = j * 256 + ((cn ^ l31) << 3) + sub;
                        *(uint2v*)(hbuf + addr) = (uint2v){
                            pack2(relu(acc[tj][q * 4]), relu(acc[tj][q * 4 + 1])),
                            pack2(relu(acc[tj][q * 4 + 2]), relu(acc[tj][q * 4 + 3]))};
                    }
                }
                lds_barrier();
#pragma unroll
                for (int tj = 0; tj < 2; ++tj)
                    bfr[0][tj] = *(const short8*)(hbuf + jb[tj] + ((h5 ^ l31) << 3));
            }
        }

        // partial pooled sum over this pass's 64 j rows:
        // col j = l31, row n = n0 + (r&3) + 8*(r>>2) + 4*h5
#pragma unroll
        for (int r = 0; r < 16; ++r) {
            float s = relu(acc[0][r]) + relu(acc[1][r]);
            s += __shfl_xor(s, 1);
            s += __shfl_xor(s, 2);
            s += __shfl_xor(s, 4);
            s += __shfl_xor(s, 8);
            s += __shfl_xor(s, 16);
            if (l31 == 0) {
                const int n = n0 + (r & 3) + 8 * (r >> 2) + 4 * h5;
                if (pass == 0) ms[n] = s;
                else           ms[n] = (ms[n] + s) * 0.0078125f;   // /128
            }
        }
    }
    __syncthreads();

    // ---- epilogue: t1 = relu(m2@W34 + b34); out = t1@wd2 + bd2
    // fs aliases hbuf (all h reads done):
    //   p1[0..2048) | t1[2048..2304) | p2[2304..2816)
    float* fs = (float*)hbuf;
    {   // stage 1: m2 @ W34, 8-way k-split (wave wv covers k in [wv*32, wv*32+32))
        float p0 = 0.f, p1 = 0.f, p2 = 0.f, p3 = 0.f;
        const float* wp = W34 + (wv * 32) * 256 + lane;
#pragma unroll 8
        for (int kk = 0; kk < 32; ++kk) {
            float mv = ms[wv * 32 + kk];
            p0 += mv * wp[kk * 256];
            p1 += mv * wp[kk * 256 + 64];
            p2 += mv * wp[kk * 256 + 128];
            p3 += mv * wp[kk * 256 + 192];
        }
        fs[wv * 256 + lane]       = p0;
        fs[wv * 256 + 64 + lane]  = p1;
        fs[wv * 256 + 128 + lane] = p2;
        fs[wv * 256 + 192 + lane] = p3;
    }
    __syncthreads();
    if (t < 256) {
        float s = b34[t];
#pragma unroll
        for (int v = 0; v < 8; ++v) s += fs[v * 256 + t];
        fs[2048 + t] = relu(s);
    }
    __syncthreads();
    {   // stage 2: t1 @ wd2 (wave wv covers k in [wv*32, wv*32+32), lane = output o)
        float p = 0.f;
        const float* w2p = wd2 + (wv * 32) * 64 + lane;
#pragma unroll 8
        for (int kk = 0; kk < 32; ++kk) p += fs[2048 + wv * 32 + kk] * w2p[kk * 64];
        fs[2304 + wv * 64 + lane] = p;
    }
    __syncthreads();
    if (t < 64) {
        float s = bd2[t];
#pragma unroll
        for (int v = 0; v < 8; ++v) s += fs[2304 + v * 64 + t];
        out[w * 64 + t] = s;
    }
}

extern "C" void kernel_launch(void* const* d_in, const int* in_sizes, int n_in,
                              void* d_out, int out_size, void* d_ws, size_t ws_size,
                              hipStream_t stream) {
    const float* x0    = (const float*)d_in[0];
    const float* x1    = (const float*)d_in[1];
    const float* x2    = (const float*)d_in[2];
    const float* w_enc = (const float*)d_in[3];
    const float* b_enc = (const float*)d_in[4];
    const float* w1    = (const float*)d_in[5];
    const float* b1    = (const float*)d_in[6];
    const float* w2    = (const float*)d_in[7];
    const float* b2    = (const float*)d_in[8];
    const float* w3    = (const float*)d_in[9];
    const float* b3    = (const float*)d_in[10];
    const float* wd1   = (const float*)d_in[11];
    const float* bd1   = (const float*)d_in[12];
    const float* wd2   = (const float*)d_in[13];
    const float* bd2   = (const float*)d_in[14];
    float* out = (float*)d_out;

    // workspace: wfrag 256KB (in 384KB slot) | ea 1MB | eb 1MB | W34 256KB | b34 1KB
    unsigned short* wt = (unsigned short*)d_ws;
    float* ea  = (float*)((char*)d_ws + 3 * 65536 * sizeof(unsigned short));
    float* eb  = ea + NROW * HID;
    float* W34 = eb + NROW * HID;
    float* b34 = W34 + 256 * 256;

    setup_kernel<<<785, 256, 0, stream>>>(x0, x1, x2, w_enc, b_enc, w1, w2,
                                          w3, b3, wd1, bd1, wt, ea, eb, W34, b34);
    pair_kernel<<<NROW, 512, 0, stream>>>(ea, eb, wt, b1, b2, W34, b34, wd2, bd2, out);
}